// Round 6
// baseline (230.933 us; speedup 1.0000x reference)
//
#include <hip/hip_runtime.h>
#include <hip/hip_bf16.h>

typedef unsigned short u16;
typedef unsigned int u32;
typedef unsigned long long u64;
typedef short bf16x8 __attribute__((ext_vector_type(8)));
typedef float f32x4  __attribute__((ext_vector_type(4)));

// RowLSTM B=32, Cin=3, H=W=64, HC=128, gates o,f,i,g (all sigmoid), c=f*c+i*g,
// h=o*tanh(c). Masked-B 1x3 conv: taps (w-1, w).
//
// Round 13: barrier-free dataflow row loop (round-12 design, hardened).
// Evidence r1/r2/r4: every vmem-ordering fix is null at ~131us; busy
// accounting (VALU ~1570cy + LDS 576cy + MFMA ~350cy vs 4900cy period) =>
// ~3000cy/row of lockstep-barrier idle. Fix: per-wave LDS flags wdone[8];
// each wave is SOLE writer of its own B-tile (kt=wid; wave 1 also x-tile 8;
// halo consumers distributed so wave w commits its own 4 halo words into its
// own tile). Readers gate EACH k-tile on that tile's writer flag => waves
// free-run with <=1-row skew; the 2 waves/SIMD desync so GEMM of one overlaps
// EW/trans of the other, and jitter is absorbed by tile slack instead of
// barrier-propagating.
// Safety: wave w's row-r k-loop observes all flags >= r (all waves done row
// r-1, incl. their reads of buffer parity (r+1)&1) BEFORE w writes that
// parity => no WAR hazard. Flag publish: lgkmcnt(0) then ds_write (drains all
// prior LDS writes). Hardened vs r12: SPIN_CAP=1<<16 (worst case ~1s total,
// fail-visible, can't look like an infra death), and the anti-hoist gate hack
// obfuscates the 32-bit LDS OFFSET (not the pointer) so B-reads keep LDS
// provenance and compile to ds_read_b128, not flat_load.
// Halo protocol = round-11 inverted words (2 MB ws, memset per launch).

__device__ __forceinline__ u16 f2b(float f) {
    return __builtin_bit_cast(u16, __float2bfloat16(f));
}
__device__ __forceinline__ float sigm(float x) {
    return __builtin_amdgcn_rcpf(1.0f + __expf(-x));
}
__device__ __forceinline__ float tanh_fast(float x) {
    return 1.0f - 2.0f * __builtin_amdgcn_rcpf(__expf(2.0f * x) + 1.0f);
}

#define LINE(kt, lane) (((kt) * 64 + (lane)) * 16)
#define BUFBYTES (9 * 64 * 16)   /* 9216 B per buffer */
#define SPIN_CAP (1 << 16)

__global__ __launch_bounds__(512, 2) void rowlstm_mfma10(
    const float* __restrict__ x,   const float* __restrict__ Wis,
    const float* __restrict__ bis, const float* __restrict__ Wss,
    const float* __restrict__ bss, const float* __restrict__ h0,
    const float* __restrict__ c0,  float* __restrict__ out,
    char* halo)
{
    __shared__ __align__(16) char lds_buf[2 * BUFBYTES];   // 18432 B
    __shared__ u16  lds_x[3 * 64 * 17];                    // 6528 B
    __shared__ float lds_bias[512];                        // 2048 B
    __shared__ u32  wdone[8];                              // per-wave row flags

    const int tid  = threadIdx.x;
    const int s    = blockIdx.x;            // w-quarter
    const int b    = blockIdx.y;            // batch
    const int wid  = tid >> 6;              // wave [0,8) = hc-tile
    const int lane = tid & 63;
    const int q    = lane >> 4;             // quad
    const int n    = lane & 15;             // w within quarter
    const int wbase = s * 16;

    // halo slot: per (b,s,r): 32 units x 8B = 256B; unit u holds ~[4xbf16 h]
    // for ic = u*4..u*4+3 of the right-edge column. word!=0 <=> valid.
    char* hs_my = halo + ((size_t)(b * 4 + s) * 64) * 256;
    char* hs_up = halo + ((size_t)(b * 4 + (s > 0 ? s - 1 : 0)) * 64) * 256;

    // ---------- phase 0: zero both B buffers + flags ----------
    for (int i = tid; i < 1152; i += 512)
        *(uint4*)(lds_buf + i * 16) = make_uint4(0, 0, 0, 0);
    if (tid < 8) wdone[tid] = 0;
    __syncthreads();

    // ---------- phase 1: one-time staging ----------
    lds_bias[tid] = bis[tid] + bss[tid];

    // x -> LDS bf16: [cch][r][wl1], wl1 = local w + 1 (col 0 = left halo col)
    for (int i = tid; i < 3264; i += 512) {
        int cch = i / 1088, rem = i % 1088;
        int r = rem / 17, wl1 = rem % 17;
        int gw = wbase + wl1 - 1;
        lds_x[i] = (gw < 0) ? (u16)0
                 : f2b(x[(((size_t)b * 3 + cch) * 64 + r) * 64 + gw]);
    }

    // A-fragments (persist in regs): a[j]=tap1(ic=kt*16+q*4+j), a[4+j]=tap0
    bf16x8 afr[4][9];
    {
        #pragma unroll
        for (int g = 0; g < 4; ++g) {
            int oc = g * 128 + wid * 16 + n;           // m = n
            #pragma unroll
            for (int kt = 0; kt < 8; ++kt) {
                bf16x8 a;
                #pragma unroll
                for (int jj = 0; jj < 4; ++jj) {
                    int ic = kt * 16 + q * 4 + jj;
                    float2 wp = *(const float2*)&Wss[(size_t)(oc * 128 + ic) * 3];
                    a[jj]     = (short)f2b(wp.y);      // tap1 (center)
                    a[4 + jj] = (short)f2b(wp.x);      // tap0 (left)
                }
                afr[g][kt] = a;
            }
            bf16x8 ax = {0, 0, 0, 0, 0, 0, 0, 0};
            if (q == 0) {
                #pragma unroll
                for (int cch = 0; cch < 3; ++cch) {
                    float2 wp = *(const float2*)&Wis[(size_t)(oc * 3 + cch) * 3];
                    ax[cch]     = (short)f2b(wp.y);
                    ax[4 + cch] = (short)f2b(wp.x);
                }
            }
            afr[g][8] = ax;
        }
    }

    // c-state (fp32, registers) + h0 publish into buf0
    float cst[4];
    {
        u16 hw[4];
        #pragma unroll
        for (int reg = 0; reg < 4; ++reg) {
            int hc = wid * 16 + q * 4 + reg;
            int wg = wbase + n;
            cst[reg] = c0[hc * 64 + wg];
            hw[reg] = f2b(h0[hc * 64 + wg]);
        }
        u64 d01 = (u64)((u32)hw[0] | ((u32)hw[1] << 16))
                | ((u64)((u32)hw[2] | ((u32)hw[3] << 16)) << 32);
        *(u64*)(lds_buf + LINE(wid, lane)) = d01;               // tap1 halves
        int wl = n + 1;
        if (wl < 16)
            *(u64*)(lds_buf + LINE(wid, q * 16 + wl) + 8) = d01;
    }
    // s>0: left-edge tap0 column from h0[:, wbase-1] (h0 is known globally)
    if (s > 0 && tid < 32) {
        int ic0 = tid * 4;
        u64 v = (u64)((u32)f2b(h0[(ic0 + 0) * 64 + wbase - 1]) | ((u32)f2b(h0[(ic0 + 1) * 64 + wbase - 1]) << 16))
              | ((u64)((u32)f2b(h0[(ic0 + 2) * 64 + wbase - 1]) | ((u32)f2b(h0[(ic0 + 3) * 64 + wbase - 1]) << 16)) << 32);
        *(u64*)(lds_buf + LINE(tid >> 2, (tid & 3) * 16) + 8) = v;
    }
    // x K-tile for row 0 into buf0 (q==0 lanes only; q>0 lanes stay zero)
    if (tid < 16) {
        int nn = tid;
        u32 d0 = (u32)lds_x[0 * 1088 + 0 * 17 + nn + 1] | ((u32)lds_x[1 * 1088 + 0 * 17 + nn + 1] << 16);
        u32 d1 = (u32)lds_x[2 * 1088 + 0 * 17 + nn + 1];
        u32 d2 = (u32)lds_x[0 * 1088 + 0 * 17 + nn]     | ((u32)lds_x[1 * 1088 + 0 * 17 + nn] << 16);
        u32 d3 = (u32)lds_x[2 * 1088 + 0 * 17 + nn];
        *(uint4*)(lds_buf + LINE(8, nn)) = make_uint4(d0, d1, d2, d3);
    }
    __syncthreads();

    // bias -> registers (constant per lane across rows)
    f32x4 bias_r[4];
    #pragma unroll
    for (int g = 0; g < 4; ++g) {
        int oc = g * 128 + wid * 16 + q * 4;
        bias_r[g][0] = lds_bias[oc + 0];
        bias_r[g][1] = lds_bias[oc + 1];
        bias_r[g][2] = lds_bias[oc + 2];
        bias_r[g][3] = lds_bias[oc + 3];
    }

    // DISTRIBUTED consumer: wave w, lanes 0..3 own halo unit (wid*4+lane),
    // committing into OWN tile (kt=wid, line lane*16, tap0 half).
    u64 hv = 0, hn = 0;
    const bool is_cons = (s > 0) && (lane < 4);
    if (is_cons)
        hv = __hip_atomic_load((const u64*)(hs_up + (size_t)(wid * 4 + lane) * 8),
                               __ATOMIC_RELAXED, __HIP_MEMORY_SCOPE_AGENT);

    // ================= row loop: NO barrier, per-tile dataflow =============
    for (int r = 0; r < 64; ++r) {
        char* rbuf = lds_buf + (r & 1) * BUFBYTES;
        char* wbuf = lds_buf + ((r & 1) ^ 1) * BUFBYTES;

        // ---- top: prefetch halo slot r+1 (validated at row r+1 bottom) ----
        if (is_cons && r < 62)
            hn = __hip_atomic_load((const u64*)(hs_up + (size_t)(r + 1) * 256 + (wid * 4 + lane) * 8),
                                   __ATOMIC_RELAXED, __HIP_MEMORY_SCOPE_AGENT);

        // ---- flag snapshot (monotone; stale-low only) ----
        u32 f[8];
        #pragma unroll
        for (int j = 0; j < 8; ++j)
            f[j] = __hip_atomic_load(&wdone[j], __ATOMIC_RELAXED,
                                     __HIP_MEMORY_SCOPE_WORKGROUP);

        // ---- GEMM: per-tile gated on the tile's writer flag ----
        f32x4 acc[4];
        acc[0] = bias_r[0]; acc[1] = bias_r[1];
        acc[2] = bias_r[2]; acc[3] = bias_r[3];
        #pragma unroll
        for (int kt = 0; kt < 9; ++kt) {
            const int g = (kt < 8) ? kt : 1;       // tile 8 (x) written by wave 1
            if (f[g] < (u32)r) {
                int guard = 0;
                do {
                    __builtin_amdgcn_s_sleep(1);
                    f[g] = __hip_atomic_load(&wdone[g], __ATOMIC_RELAXED,
                                             __HIP_MEMORY_SCOPE_WORKGROUP);
                } while (f[g] < (u32)r && ++guard < SPIN_CAP);
            }
            // forbid speculative hoist of the tile read above the gate:
            // obfuscate the 32-bit LDS offset with a dep on the flag value.
            int off = LINE(kt, lane);
            asm volatile("" : "+v"(off) : "v"(f[g]));
            bf16x8 bv = *(const bf16x8*)(rbuf + off);   // stays ds_read_b128
            acc[0] = __builtin_amdgcn_mfma_f32_16x16x32_bf16(afr[0][kt], bv, acc[0], 0, 0, 0);
            acc[1] = __builtin_amdgcn_mfma_f32_16x16x32_bf16(afr[1][kt], bv, acc[1], 0, 0, 0);
            acc[2] = __builtin_amdgcn_mfma_f32_16x16x32_bf16(afr[2][kt], bv, acc[2], 0, 0, 0);
            acc[3] = __builtin_amdgcn_mfma_f32_16x16x32_bf16(afr[3][kt], bv, acc[3], 0, 0, 0);
        }

        // ---- elementwise (D: col = n, row = q*4+reg) ----
        float hval[4]; u16 hw[4];
        #pragma unroll
        for (int reg = 0; reg < 4; ++reg) {
            float o  = sigm(acc[0][reg]);
            float f_ = sigm(acc[1][reg]);
            float ii = sigm(acc[2][reg]);
            float gg = sigm(acc[3][reg]);
            float cn = f_ * cst[reg] + ii * gg;
            cst[reg] = cn;
            float h = o * tanh_fast(cn);
            hval[reg] = h;
            hw[reg] = f2b(h);
        }

        // ---- h -> own tile of wbuf; edge lanes fire inverted halo word ----
        u64 d01 = (u64)((u32)hw[0] | ((u32)hw[1] << 16))
                | ((u64)((u32)hw[2] | ((u32)hw[3] << 16)) << 32);
        *(u64*)(wbuf + LINE(wid, lane)) = d01;                 // tap1 halves
        int wl = n + 1;
        if (wl < 16) {
            *(u64*)(wbuf + LINE(wid, q * 16 + wl) + 8) = d01;
        } else if (s < 3 && r < 63) {
            __hip_atomic_store((u64*)(hs_my + (size_t)r * 256 + (wid * 4 + q) * 8),
                               ~d01, __ATOMIC_RELAXED, __HIP_MEMORY_SCOPE_AGENT);
        }

        // ---- wave 1: x K-tile for row r+1 into wbuf tile 8 ----
        if (r < 63 && tid >= 64 && tid < 80) {
            int nn = tid - 64, r1 = r + 1;
            u32 d0 = (u32)lds_x[0 * 1088 + r1 * 17 + nn + 1] | ((u32)lds_x[1 * 1088 + r1 * 17 + nn + 1] << 16);
            u32 d1 = (u32)lds_x[2 * 1088 + r1 * 17 + nn + 1];
            u32 d2 = (u32)lds_x[0 * 1088 + r1 * 17 + nn]     | ((u32)lds_x[1 * 1088 + r1 * 17 + nn] << 16);
            u32 d3 = (u32)lds_x[2 * 1088 + r1 * 17 + nn];
            *(uint4*)(wbuf + LINE(8, nn)) = make_uint4(d0, d1, d2, d3);
        }

        // ---- consumer lanes: validate + commit halo slot r into OWN tile ----
        if (is_cons && r < 63) {
            if (hv == 0) {
                int guard = 0;
                do {
                    __builtin_amdgcn_s_sleep(1);
                    hv = __hip_atomic_load((const u64*)(hs_up + (size_t)r * 256 + (wid * 4 + lane) * 8),
                                           __ATOMIC_RELAXED, __HIP_MEMORY_SCOPE_AGENT);
                } while (hv == 0 && ++guard < SPIN_CAP);
            }
            *(u64*)(wbuf + LINE(wid, lane * 16) + 8) = ~hv;
            hv = hn;
        }

        // ---- out stores (fire-and-forget; never waited on) ----
        #pragma unroll
        for (int reg = 0; reg < 4; ++reg) {
            int hc = wid * 16 + q * 4 + reg;
            out[(((size_t)(b * 128 + hc)) * 64 + r) * 64 + wbase + n] = hval[reg];
        }

        // ---- publish: all LDS writes drained, then flag = r+1 ----
        __builtin_amdgcn_sched_barrier(0);
        asm volatile("s_waitcnt lgkmcnt(0)" ::: "memory");
        __builtin_amdgcn_sched_barrier(0);
        if (lane == 0)
            __hip_atomic_store(&wdone[wid], (u32)(r + 1), __ATOMIC_RELAXED,
                               __HIP_MEMORY_SCOPE_WORKGROUP);
        __builtin_amdgcn_sched_barrier(0);
    }
}

extern "C" void kernel_launch(void* const* d_in, const int* in_sizes, int n_in,
                              void* d_out, int out_size, void* d_ws, size_t ws_size,
                              hipStream_t stream)
{
    const float* x   = (const float*)d_in[0];
    const float* Wis = (const float*)d_in[1];
    const float* bis = (const float*)d_in[2];
    const float* Wss = (const float*)d_in[3];
    const float* bss = (const float*)d_in[4];
    const float* h0  = (const float*)d_in[5];
    const float* c0  = (const float*)d_in[6];
    float* out = (float*)d_out;

    // halo: 32 b x 4 s x 64 r x 256 B = 2 MB, write-once inverted words.
    // Must be zeroed every launch (word!=0 is the valid bit).
    hipMemsetAsync(d_ws, 0, (size_t)32 * 4 * 64 * 256, stream);
    rowlstm_mfma10<<<dim3(4, 32), 512, 0, stream>>>(
        x, Wis, bis, Wss, bss, h0, c0, out, (char*)d_ws);
}

// Round 7
// 211.053 us; speedup vs baseline: 1.0942x; 1.0942x over previous
//
#include <hip/hip_runtime.h>
#include <hip/hip_bf16.h>

typedef unsigned short u16;
typedef unsigned int u32;
typedef unsigned long long u64;
typedef short bf16x8 __attribute__((ext_vector_type(8)));
typedef float f32x4  __attribute__((ext_vector_type(4)));

// RowLSTM B=32, Cin=3, H=W=64, HC=128, gates o,f,i,g (all sigmoid), c=f*c+i*g,
// h=o*tanh(c). Masked-B 1x3 conv: taps (w-1, w).
//
// Round 14: revert to the proven round-11 base (131us; barrier-free dataflow
// REGRESSED to 160us in r13 -- all-to-all per-row deps leave no skew, and
// per-tile gates serialized the batched ds_read stream, +1100cy/row).
// This round: critical-path diet inside the proven structure:
//  - acc split even/odd kt: MFMA dep chain 9 -> 5 (+vector add at end)
//  - EW: merge sigm(i)*sigm(g) = rcp((1+ei)(1+eg)) -> 9 trans/reg (was 10);
//    saturating-safe forms only (no inf-inf/0*inf paths for |preact|<88)
//  - out[] stores DEFERRED one row: issued at next row's top, overlapping the
//    ds_read lgkmcnt wait instead of sitting on the pre-barrier path
//  - wave-1 x-staging moved AFTER the GEMM k-loop (LDS FIFO is in-order; the
//    staging reads/write were delaying wave 1's 9 B-tile reads every row ->
//    wave 1 was the per-row barrier straggler)
//  - s_setprio(1) around the MFMA k-loop (T5; stager/consumer role diversity)
// Halo protocol unchanged (round-11): inverted self-validating words, 2 MB
// workspace memset per launch, relaxed lgkmcnt-only barrier, capped spins.

__device__ __forceinline__ u16 f2b(float f) {
    return __builtin_bit_cast(u16, __float2bfloat16(f));
}

#define LINE(kt, lane) (((kt) * 64 + (lane)) * 16)
#define BUFBYTES (9 * 64 * 16)   /* 9216 B per buffer */
#define SPIN_CAP (1 << 16)

__global__ __launch_bounds__(512, 2) void rowlstm_mfma11(
    const float* __restrict__ x,   const float* __restrict__ Wis,
    const float* __restrict__ bis, const float* __restrict__ Wss,
    const float* __restrict__ bss, const float* __restrict__ h0,
    const float* __restrict__ c0,  float* __restrict__ out,
    char* halo)
{
    __shared__ __align__(16) char lds_buf[2 * BUFBYTES];   // 18432 B
    __shared__ u16  lds_x[3 * 64 * 17];                    // 6528 B
    __shared__ float lds_bias[512];                        // 2048 B

    const int tid  = threadIdx.x;
    const int s    = blockIdx.x;            // w-quarter
    const int b    = blockIdx.y;            // batch
    const int wid  = tid >> 6;              // wave [0,8) = hc-tile
    const int lane = tid & 63;
    const int q    = lane >> 4;             // quad
    const int n    = lane & 15;             // w within quarter
    const int wbase = s * 16;

    // halo slot: per (b,s,r): 32 units x 8B = 256B; unit u holds ~[4xbf16 h]
    // for ic = u*4..u*4+3 of the right-edge column. word!=0 <=> valid.
    char* hs_my = halo + ((size_t)(b * 4 + s) * 64) * 256;
    char* hs_up = halo + ((size_t)(b * 4 + (s > 0 ? s - 1 : 0)) * 64) * 256;

    // ---------- phase 0: zero both B buffers ----------
    for (int i = tid; i < 1152; i += 512)
        *(uint4*)(lds_buf + i * 16) = make_uint4(0, 0, 0, 0);
    __syncthreads();

    // ---------- phase 1: one-time staging ----------
    lds_bias[tid] = bis[tid] + bss[tid];

    // x -> LDS bf16: [cch][r][wl1], wl1 = local w + 1 (col 0 = left halo col)
    for (int i = tid; i < 3264; i += 512) {
        int cch = i / 1088, rem = i % 1088;
        int r = rem / 17, wl1 = rem % 17;
        int gw = wbase + wl1 - 1;
        lds_x[i] = (gw < 0) ? (u16)0
                 : f2b(x[(((size_t)b * 3 + cch) * 64 + r) * 64 + gw]);
    }

    // A-fragments (persist in regs): a[j]=tap1(ic=kt*16+q*4+j), a[4+j]=tap0
    bf16x8 afr[4][9];
    {
        #pragma unroll
        for (int g = 0; g < 4; ++g) {
            int oc = g * 128 + wid * 16 + n;           // m = n
            #pragma unroll
            for (int kt = 0; kt < 8; ++kt) {
                bf16x8 a;
                #pragma unroll
                for (int jj = 0; jj < 4; ++jj) {
                    int ic = kt * 16 + q * 4 + jj;
                    float2 wp = *(const float2*)&Wss[(size_t)(oc * 128 + ic) * 3];
                    a[jj]     = (short)f2b(wp.y);      // tap1 (center)
                    a[4 + jj] = (short)f2b(wp.x);      // tap0 (left)
                }
                afr[g][kt] = a;
            }
            bf16x8 ax = {0, 0, 0, 0, 0, 0, 0, 0};
            if (q == 0) {
                #pragma unroll
                for (int cch = 0; cch < 3; ++cch) {
                    float2 wp = *(const float2*)&Wis[(size_t)(oc * 3 + cch) * 3];
                    ax[cch]     = (short)f2b(wp.y);
                    ax[4 + cch] = (short)f2b(wp.x);
                }
            }
            afr[g][8] = ax;
        }
    }

    // c-state (fp32, registers) + h0 publish into buf0
    float cst[4];
    {
        u16 hw[4];
        #pragma unroll
        for (int reg = 0; reg < 4; ++reg) {
            int hc = wid * 16 + q * 4 + reg;
            int wg = wbase + n;
            cst[reg] = c0[hc * 64 + wg];
            hw[reg] = f2b(h0[hc * 64 + wg]);
        }
        u64 d01 = (u64)((u32)hw[0] | ((u32)hw[1] << 16))
                | ((u64)((u32)hw[2] | ((u32)hw[3] << 16)) << 32);
        *(u64*)(lds_buf + LINE(wid, lane)) = d01;               // tap1 halves
        int wl = n + 1;
        if (wl < 16)
            *(u64*)(lds_buf + LINE(wid, q * 16 + wl) + 8) = d01;
    }
    // s>0: left-edge tap0 column from h0[:, wbase-1] (h0 is known globally)
    if (s > 0 && tid < 32) {
        int ic0 = tid * 4;
        u64 v = (u64)((u32)f2b(h0[(ic0 + 0) * 64 + wbase - 1]) | ((u32)f2b(h0[(ic0 + 1) * 64 + wbase - 1]) << 16))
              | ((u64)((u32)f2b(h0[(ic0 + 2) * 64 + wbase - 1]) | ((u32)f2b(h0[(ic0 + 3) * 64 + wbase - 1]) << 16)) << 32);
        *(u64*)(lds_buf + LINE(tid >> 2, (tid & 3) * 16) + 8) = v;
    }
    // x K-tile for row 0 into buf0 (q==0 lanes only; q>0 lanes stay zero)
    if (tid < 16) {
        int nn = tid;
        u32 d0 = (u32)lds_x[0 * 1088 + 0 * 17 + nn + 1] | ((u32)lds_x[1 * 1088 + 0 * 17 + nn + 1] << 16);
        u32 d1 = (u32)lds_x[2 * 1088 + 0 * 17 + nn + 1];
        u32 d2 = (u32)lds_x[0 * 1088 + 0 * 17 + nn]     | ((u32)lds_x[1 * 1088 + 0 * 17 + nn] << 16);
        u32 d3 = (u32)lds_x[2 * 1088 + 0 * 17 + nn];
        *(uint4*)(lds_buf + LINE(8, nn)) = make_uint4(d0, d1, d2, d3);
    }
    __syncthreads();

    // bias -> registers (constant per lane across rows)
    f32x4 bias_r[4];
    #pragma unroll
    for (int g = 0; g < 4; ++g) {
        int oc = g * 128 + wid * 16 + q * 4;
        bias_r[g][0] = lds_bias[oc + 0];
        bias_r[g][1] = lds_bias[oc + 1];
        bias_r[g][2] = lds_bias[oc + 2];
        bias_r[g][3] = lds_bias[oc + 3];
    }

    // consumer pipeline state (tid<32 of s>0 blocks): hv = slot[r] word,
    // hn = slot[r+1] word (prefetched one row early)
    u64 hv = 0, hn = 0;
    const bool is_cons = (s > 0) && (tid < 32);
    if (is_cons)
        hv = __hip_atomic_load((const u64*)(hs_up + (size_t)tid * 8),
                               __ATOMIC_RELAXED, __HIP_MEMORY_SCOPE_AGENT);

    // deferred out-store state (row r-1's h, stored at row r top)
    float ph[4];
    const float* obase = out + (((size_t)(b * 128 + wid * 16 + q * 4)) * 64) * 64
                       + wbase + n;

    // ================= row loop: ONE relaxed barrier per row =================
    for (int r = 0; r < 64; ++r) {
        char* rbuf = lds_buf + (r & 1) * BUFBYTES;
        char* wbuf = lds_buf + ((r & 1) ^ 1) * BUFBYTES;

        // ---- top: deferred out-stores for row r-1 (overlap ds_read waits) ----
        if (r > 0) {
            #pragma unroll
            for (int reg = 0; reg < 4; ++reg)
                ((float*)obase)[(size_t)reg * 4096 + (r - 1) * 64] = ph[reg];
        }

        // ---- top: prefetch halo slot r+1 (validated at row r+1 bottom) ----
        if (is_cons && r < 62)
            hn = __hip_atomic_load((const u64*)(hs_up + (size_t)(r + 1) * 256 + tid * 8),
                                   __ATOMIC_RELAXED, __HIP_MEMORY_SCOPE_AGENT);

        // ---- GEMM (split accumulators: even/odd kt -> chain 5/4 deep) ----
        f32x4 acc[4], acc2[4];
        acc[0] = bias_r[0]; acc[1] = bias_r[1];
        acc[2] = bias_r[2]; acc[3] = bias_r[3];
        acc2[0] = (f32x4){0,0,0,0}; acc2[1] = (f32x4){0,0,0,0};
        acc2[2] = (f32x4){0,0,0,0}; acc2[3] = (f32x4){0,0,0,0};
        __builtin_amdgcn_s_setprio(1);
        #pragma unroll
        for (int kt = 0; kt < 9; ++kt) {
            bf16x8 bv = *(const bf16x8*)(rbuf + LINE(kt, lane));
            if (kt & 1) {
                acc2[0] = __builtin_amdgcn_mfma_f32_16x16x32_bf16(afr[0][kt], bv, acc2[0], 0, 0, 0);
                acc2[1] = __builtin_amdgcn_mfma_f32_16x16x32_bf16(afr[1][kt], bv, acc2[1], 0, 0, 0);
                acc2[2] = __builtin_amdgcn_mfma_f32_16x16x32_bf16(afr[2][kt], bv, acc2[2], 0, 0, 0);
                acc2[3] = __builtin_amdgcn_mfma_f32_16x16x32_bf16(afr[3][kt], bv, acc2[3], 0, 0, 0);
            } else {
                acc[0] = __builtin_amdgcn_mfma_f32_16x16x32_bf16(afr[0][kt], bv, acc[0], 0, 0, 0);
                acc[1] = __builtin_amdgcn_mfma_f32_16x16x32_bf16(afr[1][kt], bv, acc[1], 0, 0, 0);
                acc[2] = __builtin_amdgcn_mfma_f32_16x16x32_bf16(afr[2][kt], bv, acc[2], 0, 0, 0);
                acc[3] = __builtin_amdgcn_mfma_f32_16x16x32_bf16(afr[3][kt], bv, acc[3], 0, 0, 0);
            }
        }
        __builtin_amdgcn_s_setprio(0);
        acc[0] += acc2[0]; acc[1] += acc2[1];
        acc[2] += acc2[2]; acc[3] += acc2[3];

        // ---- wave 1: x K-tile for row r+1 into wbuf (after its B-reads) ----
        if (r < 63 && tid >= 64 && tid < 80) {
            int nn = tid - 64, r1 = r + 1;
            u32 d0 = (u32)lds_x[0 * 1088 + r1 * 17 + nn + 1] | ((u32)lds_x[1 * 1088 + r1 * 17 + nn + 1] << 16);
            u32 d1 = (u32)lds_x[2 * 1088 + r1 * 17 + nn + 1];
            u32 d2 = (u32)lds_x[0 * 1088 + r1 * 17 + nn]     | ((u32)lds_x[1 * 1088 + r1 * 17 + nn] << 16);
            u32 d3 = (u32)lds_x[2 * 1088 + r1 * 17 + nn];
            *(uint4*)(wbuf + LINE(8, nn)) = make_uint4(d0, d1, d2, d3);
        }

        // ---- elementwise (D: col = n, row = q*4+reg) ----
        // o,f,i,g all sigmoid; sig(i)*sig(g) merged: rcp((1+ei)(1+eg)).
        // Saturating-safe for |preact| < ~88 (data: |a| <~ 6).
        u16 hw[4];
        #pragma unroll
        for (int reg = 0; reg < 4; ++reg) {
            float eo = __expf(-acc[0][reg]);
            float ef = __expf(-acc[1][reg]);
            float ei = __expf(-acc[2][reg]);
            float eg = __expf(-acc[3][reg]);
            float f_ = __builtin_amdgcn_rcpf(1.0f + ef);
            float t  = 1.0f + ei;
            float ig = __builtin_amdgcn_rcpf(t + eg * t);   // sig(i)*sig(g)
            float cn = f_ * cst[reg] + ig;
            cst[reg] = cn;
            float o_ = __builtin_amdgcn_rcpf(1.0f + eo);
            float e2 = __expf(2.0f * cn);
            float th = 1.0f - 2.0f * __builtin_amdgcn_rcpf(e2 + 1.0f);
            float h  = o_ * th;
            ph[reg] = h;
            hw[reg] = f2b(h);
        }

        // ---- h -> LDS (wbuf); edge lanes fire inverted halo word ----
        u64 d01 = (u64)((u32)hw[0] | ((u32)hw[1] << 16))
                | ((u64)((u32)hw[2] | ((u32)hw[3] << 16)) << 32);
        *(u64*)(wbuf + LINE(wid, lane)) = d01;                 // tap1 halves
        int wl = n + 1;
        if (wl < 16) {
            *(u64*)(wbuf + LINE(wid, q * 16 + wl) + 8) = d01;
        } else if (s < 3 && r < 63) {
            // fire-and-forget: ~data (nonzero for all finite h) = valid
            __hip_atomic_store((u64*)(hs_my + (size_t)r * 256 + (wid * 4 + q) * 8),
                               ~d01, __ATOMIC_RELAXED, __HIP_MEMORY_SCOPE_AGENT);
        }

        // ---- consumer: validate + commit slot r (loaded at row r-1 top) ----
        if (is_cons && r < 63) {
            if (hv == 0) {
                int guard = 0;
                do {
                    __builtin_amdgcn_s_sleep(1);               // fill only
                    hv = __hip_atomic_load((const u64*)(hs_up + (size_t)r * 256 + tid * 8),
                                           __ATOMIC_RELAXED, __HIP_MEMORY_SCOPE_AGENT);
                } while (hv == 0 && ++guard < SPIN_CAP);
            }
            *(u64*)(wbuf + LINE(tid >> 2, (tid & 3) * 16) + 8) = ~hv;
            hv = hn;
        }

        // ---- relaxed barrier: order LDS only (no vmem drain) ----
        __builtin_amdgcn_sched_barrier(0);
        asm volatile("s_waitcnt lgkmcnt(0)\n\ts_barrier" ::: "memory");
        __builtin_amdgcn_sched_barrier(0);
    }

    // tail: row 63's deferred out-stores
    #pragma unroll
    for (int reg = 0; reg < 4; ++reg)
        ((float*)obase)[(size_t)reg * 4096 + 63 * 64] = ph[reg];
}

extern "C" void kernel_launch(void* const* d_in, const int* in_sizes, int n_in,
                              void* d_out, int out_size, void* d_ws, size_t ws_size,
                              hipStream_t stream)
{
    const float* x   = (const float*)d_in[0];
    const float* Wis = (const float*)d_in[1];
    const float* bis = (const float*)d_in[2];
    const float* Wss = (const float*)d_in[3];
    const float* bss = (const float*)d_in[4];
    const float* h0  = (const float*)d_in[5];
    const float* c0  = (const float*)d_in[6];
    float* out = (float*)d_out;

    // halo: 32 b x 4 s x 64 r x 256 B = 2 MB, write-once inverted words.
    // Must be zeroed every launch (word!=0 is the valid bit).
    hipMemsetAsync(d_ws, 0, (size_t)32 * 4 * 64 * 256, stream);
    rowlstm_mfma11<<<dim3(4, 32), 512, 0, stream>>>(
        x, Wis, bis, Wss, bss, h0, c0, out, (char*)d_ws);
}

// Round 8
// 202.824 us; speedup vs baseline: 1.1386x; 1.0406x over previous
//
#include <hip/hip_runtime.h>
#include <hip/hip_bf16.h>

typedef unsigned short u16;
typedef unsigned int u32;
typedef unsigned long long u64;
typedef short bf16x8 __attribute__((ext_vector_type(8)));
typedef float f32x4  __attribute__((ext_vector_type(4)));

// RowLSTM B=32, Cin=3, H=W=64, HC=128, gates o,f,i,g (all sigmoid), c=f*c+i*g,
// h=o*tanh(c). Masked-B 1x3 conv: taps (w-1, w).
//
// Round 15: r4 base (131us, best) + x-tile PRECOMPUTE.
// Evidence: r7's +5% insts -> +3.4% time at pinned MfmaUtil/VALUBusy =>
// issue-proportional regime (likely low effective clock); sync levers all
// null. So: remove instructions, especially from the straggler wave. The x
// K-tile (kt=8) is row-constant: all 64 rows' packed tiles are built ONCE in
// phase 1 into a static 16KB LDS array x_pk[64][16]x16B; the k-loop reads
// x_pk[r][n] directly (same addr across quads -> LDS broadcast; q>0 lanes'
// values are multiplied by zero A-fragments, so sharing n's slot is exact).
// Deletes wave-1's 28-inst/row staging (the per-row barrier straggler),
// shrinks the double buffers 9216->8192B, removes row-0 tile build.
// Everything else = round-4 exactly: inverted self-validating halo words
// (2MB ws, memset/launch), relaxed lgkmcnt-only barrier, capped spins,
// no setprio / no acc-split / original EW (r7 extras reverted: -3.4%).

__device__ __forceinline__ u16 f2b(float f) {
    return __builtin_bit_cast(u16, __float2bfloat16(f));
}
__device__ __forceinline__ float sigm(float x) {
    return __builtin_amdgcn_rcpf(1.0f + __expf(-x));
}
__device__ __forceinline__ float tanh_fast(float x) {
    return 1.0f - 2.0f * __builtin_amdgcn_rcpf(__expf(2.0f * x) + 1.0f);
}

#define LINE(kt, lane) (((kt) * 64 + (lane)) * 16)
#define BUFBYTES (8 * 64 * 16)   /* 8192 B per buffer (tiles 0..7) */
#define SPIN_CAP (1 << 16)

__global__ __launch_bounds__(512, 2) void rowlstm_mfma12(
    const float* __restrict__ x,   const float* __restrict__ Wis,
    const float* __restrict__ bis, const float* __restrict__ Wss,
    const float* __restrict__ bss, const float* __restrict__ h0,
    const float* __restrict__ c0,  float* __restrict__ out,
    char* halo)
{
    __shared__ __align__(16) char lds_buf[2 * BUFBYTES];   // 16384 B
    __shared__ __align__(16) char lds_xpk[64 * 16 * 16];   // 16384 B (x K-tiles)
    __shared__ u16  lds_x[3 * 64 * 17];                    // 6528 B
    __shared__ float lds_bias[512];                        // 2048 B

    const int tid  = threadIdx.x;
    const int s    = blockIdx.x;            // w-quarter
    const int b    = blockIdx.y;            // batch
    const int wid  = tid >> 6;              // wave [0,8) = hc-tile
    const int lane = tid & 63;
    const int q    = lane >> 4;             // quad
    const int n    = lane & 15;             // w within quarter
    const int wbase = s * 16;

    // halo slot: per (b,s,r): 32 units x 8B = 256B; unit u holds ~[4xbf16 h]
    // for ic = u*4..u*4+3 of the right-edge column. word!=0 <=> valid.
    char* hs_my = halo + ((size_t)(b * 4 + s) * 64) * 256;
    char* hs_up = halo + ((size_t)(b * 4 + (s > 0 ? s - 1 : 0)) * 64) * 256;

    // ---------- phase 0: zero both B buffers ----------
    for (int i = tid; i < 1024; i += 512)
        *(uint4*)(lds_buf + i * 16) = make_uint4(0, 0, 0, 0);
    __syncthreads();

    // ---------- phase 1: one-time staging ----------
    lds_bias[tid] = bis[tid] + bss[tid];

    // x -> LDS bf16: [cch][r][wl1], wl1 = local w + 1 (col 0 = left halo col)
    for (int i = tid; i < 3264; i += 512) {
        int cch = i / 1088, rem = i % 1088;
        int r = rem / 17, wl1 = rem % 17;
        int gw = wbase + wl1 - 1;
        lds_x[i] = (gw < 0) ? (u16)0
                 : f2b(x[(((size_t)b * 3 + cch) * 64 + r) * 64 + gw]);
    }

    // A-fragments (persist in regs): a[j]=tap1(ic=kt*16+q*4+j), a[4+j]=tap0
    bf16x8 afr[4][9];
    {
        #pragma unroll
        for (int g = 0; g < 4; ++g) {
            int oc = g * 128 + wid * 16 + n;           // m = n
            #pragma unroll
            for (int kt = 0; kt < 8; ++kt) {
                bf16x8 a;
                #pragma unroll
                for (int jj = 0; jj < 4; ++jj) {
                    int ic = kt * 16 + q * 4 + jj;
                    float2 wp = *(const float2*)&Wss[(size_t)(oc * 128 + ic) * 3];
                    a[jj]     = (short)f2b(wp.y);      // tap1 (center)
                    a[4 + jj] = (short)f2b(wp.x);      // tap0 (left)
                }
                afr[g][kt] = a;
            }
            bf16x8 ax = {0, 0, 0, 0, 0, 0, 0, 0};
            if (q == 0) {
                #pragma unroll
                for (int cch = 0; cch < 3; ++cch) {
                    float2 wp = *(const float2*)&Wis[(size_t)(oc * 3 + cch) * 3];
                    ax[cch]     = (short)f2b(wp.y);
                    ax[4 + cch] = (short)f2b(wp.x);
                }
            }
            afr[g][8] = ax;
        }
    }

    // c-state (fp32, registers) + h0 publish into buf0
    float cst[4];
    {
        u16 hw[4];
        #pragma unroll
        for (int reg = 0; reg < 4; ++reg) {
            int hc = wid * 16 + q * 4 + reg;
            int wg = wbase + n;
            cst[reg] = c0[hc * 64 + wg];
            hw[reg] = f2b(h0[hc * 64 + wg]);
        }
        u64 d01 = (u64)((u32)hw[0] | ((u32)hw[1] << 16))
                | ((u64)((u32)hw[2] | ((u32)hw[3] << 16)) << 32);
        *(u64*)(lds_buf + LINE(wid, lane)) = d01;               // tap1 halves
        int wl = n + 1;
        if (wl < 16)
            *(u64*)(lds_buf + LINE(wid, q * 16 + wl) + 8) = d01;
    }
    // s>0: left-edge tap0 column from h0[:, wbase-1] (h0 is known globally)
    if (s > 0 && tid < 32) {
        int ic0 = tid * 4;
        u64 v = (u64)((u32)f2b(h0[(ic0 + 0) * 64 + wbase - 1]) | ((u32)f2b(h0[(ic0 + 1) * 64 + wbase - 1]) << 16))
              | ((u64)((u32)f2b(h0[(ic0 + 2) * 64 + wbase - 1]) | ((u32)f2b(h0[(ic0 + 3) * 64 + wbase - 1]) << 16)) << 32);
        *(u64*)(lds_buf + LINE(tid >> 2, (tid & 3) * 16) + 8) = v;
    }

    // ensure lds_x fully written before packing x_pk
    __syncthreads();

    // x_pk[r][n] 16B = packed x K-tile value for (row r, col n):
    // [cch0|cch1 tap1, cch2 tap1, cch0|cch1 tap0, cch2 tap0]
    // 1024 slots / 512 threads = 2 each.
    #pragma unroll
    for (int t = 0; t < 2; ++t) {
        int slot = tid + t * 512;
        int r = slot >> 4, nn = slot & 15;
        u32 d0 = (u32)lds_x[0 * 1088 + r * 17 + nn + 1] | ((u32)lds_x[1 * 1088 + r * 17 + nn + 1] << 16);
        u32 d1 = (u32)lds_x[2 * 1088 + r * 17 + nn + 1];
        u32 d2 = (u32)lds_x[0 * 1088 + r * 17 + nn]     | ((u32)lds_x[1 * 1088 + r * 17 + nn] << 16);
        u32 d3 = (u32)lds_x[2 * 1088 + r * 17 + nn];
        *(uint4*)(lds_xpk + slot * 16) = make_uint4(d0, d1, d2, d3);
    }
    __syncthreads();

    // bias -> registers (constant per lane across rows)
    f32x4 bias_r[4];
    #pragma unroll
    for (int g = 0; g < 4; ++g) {
        int oc = g * 128 + wid * 16 + q * 4;
        bias_r[g][0] = lds_bias[oc + 0];
        bias_r[g][1] = lds_bias[oc + 1];
        bias_r[g][2] = lds_bias[oc + 2];
        bias_r[g][3] = lds_bias[oc + 3];
    }

    // consumer pipeline state (tid<32 of s>0 blocks): hv = slot[r] word,
    // hn = slot[r+1] word (prefetched one row early)
    u64 hv = 0, hn = 0;
    const bool is_cons = (s > 0) && (tid < 32);
    if (is_cons)
        hv = __hip_atomic_load((const u64*)(hs_up + (size_t)tid * 8),
                               __ATOMIC_RELAXED, __HIP_MEMORY_SCOPE_AGENT);

    // ================= row loop: ONE relaxed barrier per row =================
    for (int r = 0; r < 64; ++r) {
        char* rbuf = lds_buf + (r & 1) * BUFBYTES;
        char* wbuf = lds_buf + ((r & 1) ^ 1) * BUFBYTES;

        // ---- top: prefetch halo slot r+1 (validated at row r+1 bottom) ----
        if (is_cons && r < 62)
            hn = __hip_atomic_load((const u64*)(hs_up + (size_t)(r + 1) * 256 + tid * 8),
                                   __ATOMIC_RELAXED, __HIP_MEMORY_SCOPE_AGENT);

        // ---- GEMM: 8 h-tiles from rbuf + static x-tile from x_pk[r] ----
        f32x4 acc[4];
        acc[0] = bias_r[0]; acc[1] = bias_r[1];
        acc[2] = bias_r[2]; acc[3] = bias_r[3];
        #pragma unroll
        for (int kt = 0; kt < 9; ++kt) {
            bf16x8 bv = (kt < 8)
                ? *(const bf16x8*)(rbuf + LINE(kt, lane))
                : *(const bf16x8*)(lds_xpk + r * 256 + n * 16);  // quad-broadcast
            acc[0] = __builtin_amdgcn_mfma_f32_16x16x32_bf16(afr[0][kt], bv, acc[0], 0, 0, 0);
            acc[1] = __builtin_amdgcn_mfma_f32_16x16x32_bf16(afr[1][kt], bv, acc[1], 0, 0, 0);
            acc[2] = __builtin_amdgcn_mfma_f32_16x16x32_bf16(afr[2][kt], bv, acc[2], 0, 0, 0);
            acc[3] = __builtin_amdgcn_mfma_f32_16x16x32_bf16(afr[3][kt], bv, acc[3], 0, 0, 0);
        }

        // ---- elementwise (D: col = n, row = q*4+reg) ----
        float hval[4]; u16 hw[4];
        #pragma unroll
        for (int reg = 0; reg < 4; ++reg) {
            float o  = sigm(acc[0][reg]);
            float f  = sigm(acc[1][reg]);
            float ii = sigm(acc[2][reg]);
            float gg = sigm(acc[3][reg]);
            float cn = f * cst[reg] + ii * gg;
            cst[reg] = cn;
            float h = o * tanh_fast(cn);
            hval[reg] = h;
            hw[reg] = f2b(h);
        }

        // ---- h -> LDS (wbuf); edge lanes fire inverted halo word ----
        u64 d01 = (u64)((u32)hw[0] | ((u32)hw[1] << 16))
                | ((u64)((u32)hw[2] | ((u32)hw[3] << 16)) << 32);
        *(u64*)(wbuf + LINE(wid, lane)) = d01;                 // tap1 halves
        int wl = n + 1;
        if (wl < 16) {
            *(u64*)(wbuf + LINE(wid, q * 16 + wl) + 8) = d01;
        } else if (s < 3 && r < 63) {
            // fire-and-forget: ~data (nonzero for all finite h) = valid
            __hip_atomic_store((u64*)(hs_my + (size_t)r * 256 + (wid * 4 + q) * 8),
                               ~d01, __ATOMIC_RELAXED, __HIP_MEMORY_SCOPE_AGENT);
        }

        // ---- out stores (fire-and-forget; never waited on) ----
        #pragma unroll
        for (int reg = 0; reg < 4; ++reg) {
            int hc = wid * 16 + q * 4 + reg;
            out[(((size_t)(b * 128 + hc)) * 64 + r) * 64 + wbase + n] = hval[reg];
        }

        // ---- consumer: validate + commit slot r (loaded at row r-1 top) ----
        if (is_cons && r < 63) {
            if (hv == 0) {
                int guard = 0;
                do {
                    __builtin_amdgcn_s_sleep(1);               // fill only
                    hv = __hip_atomic_load((const u64*)(hs_up + (size_t)r * 256 + tid * 8),
                                           __ATOMIC_RELAXED, __HIP_MEMORY_SCOPE_AGENT);
                } while (hv == 0 && ++guard < SPIN_CAP);
            }
            *(u64*)(wbuf + LINE(tid >> 2, (tid & 3) * 16) + 8) = ~hv;
            hv = hn;
        }

        // ---- relaxed barrier: order LDS only (no vmem drain) ----
        __builtin_amdgcn_sched_barrier(0);
        asm volatile("s_waitcnt lgkmcnt(0)\n\ts_barrier" ::: "memory");
        __builtin_amdgcn_sched_barrier(0);
    }
}

extern "C" void kernel_launch(void* const* d_in, const int* in_sizes, int n_in,
                              void* d_out, int out_size, void* d_ws, size_t ws_size,
                              hipStream_t stream)
{
    const float* x   = (const float*)d_in[0];
    const float* Wis = (const float*)d_in[1];
    const float* bis = (const float*)d_in[2];
    const float* Wss = (const float*)d_in[3];
    const float* bss = (const float*)d_in[4];
    const float* h0  = (const float*)d_in[5];
    const float* c0  = (const float*)d_in[6];
    float* out = (float*)d_out;

    // halo: 32 b x 4 s x 64 r x 256 B = 2 MB, write-once inverted words.
    // Must be zeroed every launch (word!=0 is the valid bit).
    hipMemsetAsync(d_ws, 0, (size_t)32 * 4 * 64 * 256, stream);
    rowlstm_mfma12<<<dim3(4, 32), 512, 0, stream>>>(
        x, Wis, bis, Wss, bss, h0, c0, out, (char*)d_ws);
}